// Round 1
// 28.538 us; speedup vs baseline: 1.0347x; 1.0347x over previous
//
#include <hip/hip_runtime.h>

// Chamfer loss: B=8, V=4, N=2048, D=3 fp32.
// final = per_view[0] + sum_v per_view[v]; per_view = mean_b(cham_x + cham_y)
// => weight per (b,v,dir) job = ((v==0)?2:1)/8.
//
// d2 = |x|^2 + |y|^2 - 2 x.y ; y staged in LDS as (y, -0.5|y|^2);
// t = x.y - 0.5|y|^2 (3 FMA); min d2 over m <=> max t; v_max3 over m-pairs.
//
// R6 restructure: block = 128 rows x ALL 2048 cols (full y set in 33KB LDS,
// 16 strips x 129-float4 pitch -> 4 strips/wave on distinct banks).
// 16 strip-threads share the same 8 rows -> row-max completes IN-BLOCK via a
// one-time 16-way LDS reduce. Eliminates the 8MB partial round-trip and the
// combine dispatch entirely (3 -> 2 dispatches).
// XCD swizzle: job j's 16 row-chunk blocks all on XCD j>>3 (y L2 reuse).

#define B_ 8
#define V_ 4
#define N_ 2048
#define JOBS 64            // B*V * 2 directions
#define RCH 16             // row-chunks per job -> 1024 blocks (4/CU)
#define RPB 128            // rows per block
#define STRIPS 16
#define SCOLS 128          // cols per strip
#define SPITCH (SCOLS + 1) // float4 pitch: strip stride 2064B de-banks strips
#define RPITCH 132         // float pitch for strip-partial reduce (writer 4-way max)
#define GRID_ (JOBS * RCH)

__global__ __launch_bounds__(256, 4) void chamfer_main(
    const float* __restrict__ X, const float* __restrict__ T,
    float* __restrict__ bsum) {
  __shared__ float4 yl[STRIPS * SPITCH];  // 33024 B; aliased for reductions
  __shared__ float red4[4];
  // XCD swizzle: physical p -> XCD p&7. Logical bid grouped so XCD x owns
  // bids [x*128,(x+1)*128) = jobs [x*8,(x+1)*8).
  const int p = blockIdx.x;
  const int bid = (p & 7) * (GRID_ / 8) + (p >> 3);
  const int job = bid >> 4;          // [0,64)
  const int rc  = bid & 15;          // row-chunk
  const int pair = job >> 1;         // b*V + v
  const int dir  = job & 1;          // 0: rows=X cols=T (cham_x), 1: swapped
  const float* xb = (dir ? T : X) + (size_t)pair * N_ * 3;
  const float* yb = (dir ? X : T) + (size_t)pair * N_ * 3;
  const int t = threadIdx.x;
  const int s  = t >> 4;             // strip [0,16)
  const int rg = t & 15;             // row-group [0,16)

  // Stage ALL 2048 y points: thread t loads points 8t..8t+7 (96B contiguous,
  // 6x float4) -> its own strip s, cols rg*8..rg*8+7.
  {
    float b[24];
    const float4* ys = (const float4*)(yb) + t * 6;
#pragma unroll
    for (int k = 0; k < 6; ++k) *(float4*)(b + 4 * k) = ys[k];
#pragma unroll
    for (int k = 0; k < 8; ++k) {
      const float a0 = b[3 * k], a1 = b[3 * k + 1], a2 = b[3 * k + 2];
      yl[s * SPITCH + rg * 8 + k] =
          make_float4(a0, a1, a2, -0.5f * fmaf(a0, a0, fmaf(a1, a1, a2 * a2)));
    }
  }

  // x rows: 8 contiguous rows (96B, 6x float4). Note: the 16 strip-threads of
  // a given rg load the SAME rows (redundant, L1-broadcast) -- by design, so
  // the row-max cross-strip combine is a cheap one-time LDS reduce.
  float x0[8], x1[8], x2[8], mt[8];
  {
    float b[24];
    const float4* xs = (const float4*)(xb + (size_t)(rc * RPB + rg * 8) * 3);
#pragma unroll
    for (int k = 0; k < 6; ++k) *(float4*)(b + 4 * k) = xs[k];
#pragma unroll
    for (int i = 0; i < 8; ++i) {
      x0[i] = b[3 * i]; x1[i] = b[3 * i + 1]; x2[i] = b[3 * i + 2];
      mt[i] = -1e30f;
    }
  }
  __syncthreads();

  // Main loop: identical cost shape to R5 (48 FMA + 8 max3 + 2 ds_read_b128
  // per 2-col step), explicit register double-buffer. Lanes of a wave read 4
  // distinct strips -> 16-lane broadcast, banks {4m,4m+4,4m+8,4m+12}: clean.
  const float4* yp = yl + s * SPITCH;
  float4 ya = yp[0], yc = yp[1];
#pragma unroll 2
  for (int m = 0; m < SCOLS; m += 2) {
    const int mn = (m + 2) & (SCOLS - 1);  // wraps on last iter (harmless)
    const float4 na = yp[mn];
    const float4 nc = yp[mn + 1];
#pragma unroll
    for (int i = 0; i < 8; ++i) {
      const float ta = fmaf(x0[i], ya.x, fmaf(x1[i], ya.y, fmaf(x2[i], ya.z, ya.w)));
      const float tc = fmaf(x0[i], yc.x, fmaf(x1[i], yc.y, fmaf(x2[i], yc.z, yc.w)));
      mt[i] = fmaxf(fmaxf(mt[i], ta), tc);  // -> v_max3_f32
    }
    ya = na;
    yc = nc;
  }

  // In-block finish: strip partials -> full row-max -> d2 -> weighted block sum.
  __syncthreads();                       // all strips done reading yl
  float* red  = (float*)yl;              // [STRIPS][RPITCH] strip-major
  float* xn2s = red + STRIPS * RPITCH;   // 128 floats (8.96KB total, fits in yl)
#pragma unroll
  for (int i = 0; i < 8; ++i) red[s * RPITCH + rg * 8 + i] = mt[i];
  if (s == 0) {
#pragma unroll
    for (int i = 0; i < 8; ++i)
      xn2s[rg * 8 + i] = fmaf(x0[i], x0[i], fmaf(x1[i], x1[i], x2[i] * x2[i]));
  }
  __syncthreads();

  float d = 0.0f;
  if (t < RPB) {                         // reader: lanes consecutive, no conflict
    float mx = red[t];
#pragma unroll
    for (int ss = 1; ss < STRIPS; ++ss) mx = fmaxf(mx, red[ss * RPITCH + t]);
    d = fmaf(-2.0f, mx, xn2s[t]);        // min d2 for this row
  }
  const int v = pair & (V_ - 1);
  const float w = ((v == 0) ? 2.0f : 1.0f) * (1.0f / (float)B_);
  float sv = d;                          // threads >=128 contribute 0
#pragma unroll
  for (int o = 32; o > 0; o >>= 1) sv += __shfl_down(sv, o, 64);
  const int lane = t & 63, wid = t >> 6;
  if (lane == 0) red4[wid] = sv;
  __syncthreads();
  if (t == 0) bsum[bid] = (red4[0] + red4[1] + red4[2] + red4[3]) * w;
}

__global__ __launch_bounds__(256) void chamfer_final(
    const float* __restrict__ bsum, float* __restrict__ out) {
  __shared__ float red4[4];
  const int t = threadIdx.x;
  float v = (bsum[t] + bsum[t + 256]) + (bsum[t + 512] + bsum[t + 768]);
#pragma unroll
  for (int o = 32; o > 0; o >>= 1) v += __shfl_down(v, o, 64);
  const int lane = t & 63, wid = t >> 6;
  if (lane == 0) red4[wid] = v;
  __syncthreads();
  if (t == 0) out[0] = (red4[0] + red4[1]) + (red4[2] + red4[3]);
}

extern "C" void kernel_launch(void* const* d_in, const int* in_sizes, int n_in,
                              void* d_out, int out_size, void* d_ws, size_t ws_size,
                              hipStream_t stream) {
  const float* X = (const float*)d_in[0];
  const float* T = (const float*)d_in[1];
  float* out = (float*)d_out;
  float* bsum = (float*)d_ws;  // 1024 floats, fully overwritten each launch

  chamfer_main<<<GRID_, 256, 0, stream>>>(X, T, bsum);
  chamfer_final<<<1, 256, 0, stream>>>(bsum, out);
}

// Round 2
// 20.355 us; speedup vs baseline: 1.4506x; 1.4020x over previous
//
#include <hip/hip_runtime.h>

// Chamfer loss: B=8, V=4, N=2048, D=3 fp32.
// final = per_view[0] + sum_v per_view[v]; per_view = mean_b(cham_x + cham_y)
// => weight per (b,v,dir) job = ((v==0)?2:1)/8.
//
// R7: MFMA rewrite. dot(x,y) via 4-term bf16 split (xh+xl)(yh+yl) inside
// mfma_f32_32x32x16_bf16, with -0.5|y|^2 folded in as fp32-accurate (wh,wl)
// K-slots against A=1.0.  t = x.y - 0.5|y|^2 ; min d2 <=> max t ;
// d2 = |x|^2 - 2t with |x|^2 kept in fp32 registers.
// K-slot map (A/B share it, so any k-permutation cancels):
//  k0-2: xh*yh  k3-5: xh*yl  k6-8: xl*yh  k9: 1*wh  k10: 1*wl  k11-13: xl*yl
// Block = 256 thr (4 waves), wave owns 64 rows (2 row-tiles of 32), all 2048
// cols via 4x 512-col LDS chunks (double-buffered, 2x24KB, 48B/col pitch ->
// uniform bank access on the b128 frag reads). Row-max finished in-register
// (butterfly over the 32-lane half that owns the row). 512 blocks = 2/CU.

#define B_ 8
#define V_ 4
#define N_ 2048
#define JOBS 64
#define RPB 256                       // rows per block
#define GRID_ (JOBS * (N_ / RPB))     // 512
#define CHUNK 512                     // cols per LDS chunk
#define NCHUNK (N_ / CHUNK)           // 4
#define CPITCH 24                     // ushorts per col (48 B): 16 data + 8 pad

typedef short bf16x8 __attribute__((ext_vector_type(8)));
typedef float f32x16 __attribute__((ext_vector_type(16)));

__device__ __forceinline__ unsigned short f2bf(float f) {
  union { float f; unsigned u; } v; v.f = f;
  const unsigned r = v.u + 0x7fffu + ((v.u >> 16) & 1u);  // RNE, same as v_cvt
  return (unsigned short)(r >> 16);
}
__device__ __forceinline__ float bf2f(unsigned short h) {
  union { unsigned u; float f; } v; v.u = ((unsigned)h) << 16;
  return v.f;
}

__device__ __forceinline__ void pack_col(float y0, float y1, float y2,
                                         unsigned short* dst) {
  const unsigned short h0 = f2bf(y0), h1 = f2bf(y1), h2 = f2bf(y2);
  const unsigned short l0 = f2bf(y0 - bf2f(h0));
  const unsigned short l1 = f2bf(y1 - bf2f(h1));
  const unsigned short l2 = f2bf(y2 - bf2f(h2));
  const float w = -0.5f * fmaf(y0, y0, fmaf(y1, y1, y2 * y2));
  const unsigned short wh = f2bf(w);
  const unsigned short wl = f2bf(w - bf2f(wh));
  bf16x8 b0, b1;
  b0[0] = (short)h0; b0[1] = (short)h1; b0[2] = (short)h2;   // k0-2
  b0[3] = (short)l0; b0[4] = (short)l1; b0[5] = (short)l2;   // k3-5
  b0[6] = (short)h0; b0[7] = (short)h1;                      // k6-7
  b1[0] = (short)h2;                                         // k8
  b1[1] = (short)wh; b1[2] = (short)wl;                      // k9-10
  b1[3] = (short)l0; b1[4] = (short)l1; b1[5] = (short)l2;   // k11-13
  b1[6] = 0; b1[7] = 0;                                      // k14-15
  *(bf16x8*)(dst) = b0;        // ds_write_b128, 16B-aligned (pitch 48)
  *(bf16x8*)(dst + 8) = b1;
}

__device__ __forceinline__ void stage_chunk(const float* __restrict__ yb,
                                            unsigned short* __restrict__ dstbuf,
                                            int ch, int t) {
  const int c0 = ch * CHUNK + t * 2;                  // 2 cols per thread
  const float2* yp2 = (const float2*)(yb + (size_t)c0 * 3);  // 8B-aligned
  const float2 u0 = yp2[0], u1 = yp2[1], u2 = yp2[2];
  unsigned short* dst = dstbuf + (size_t)(t * 2) * CPITCH;
  pack_col(u0.x, u0.y, u1.x, dst);
  pack_col(u1.y, u2.x, u2.y, dst + CPITCH);
}

__global__ __launch_bounds__(256, 2) void chamfer_main(
    const float* __restrict__ X, const float* __restrict__ T,
    float* __restrict__ bsum) {
  __shared__ unsigned short yf[2][CHUNK * CPITCH];  // 2 x 24 KB
  __shared__ float red4[4];

  // XCD swizzle: physical p -> XCD p&7; XCD x owns logical [x*64,(x+1)*64)
  // = 8 consecutive jobs (y/x panels L2-resident per XCD).
  const int p = blockIdx.x;
  const int bid = (p & 7) * (GRID_ / 8) + (p >> 3);
  const int job = bid >> 3;          // [0,64): 8 blocks per job
  const int rc  = bid & 7;           // row-chunk of 256
  const int pair = job >> 1;
  const int dir  = job & 1;          // 0: rows=X cols=T (cham_x), 1: swapped
  const float* xb = (dir ? T : X) + (size_t)pair * N_ * 3;
  const float* yb = (dir ? X : T) + (size_t)pair * N_ * 3;
  const int t = threadIdx.x;
  const int lane = t & 63;
  const int wv = t >> 6;
  const int lr = lane & 31;          // A-row / B-col within tile
  const int g  = lane >> 5;          // K-group (which 8 k-slots this lane feeds)

  // ---- A fragments: this wave's 64 rows = 2 row-tiles of 32 ----
  bf16x8 afrag[2];
  float xn2[2];
  const int rbase = rc * RPB + wv * 64;
#pragma unroll
  for (int rt = 0; rt < 2; ++rt) {
    const int r = rbase + rt * 32 + lr;
    const float x0 = xb[r * 3 + 0], x1 = xb[r * 3 + 1], x2 = xb[r * 3 + 2];
    xn2[rt] = fmaf(x0, x0, fmaf(x1, x1, x2 * x2));
    const unsigned short h0 = f2bf(x0), h1 = f2bf(x1), h2 = f2bf(x2);
    const unsigned short l0 = f2bf(x0 - bf2f(h0));
    const unsigned short l1 = f2bf(x1 - bf2f(h1));
    const unsigned short l2 = f2bf(x2 - bf2f(h2));
    const unsigned short ONE = 0x3F80;  // bf16 1.0
    bf16x8 a;
    if (g == 0) {  // k0-7
      a[0] = (short)h0; a[1] = (short)h1; a[2] = (short)h2;
      a[3] = (short)h0; a[4] = (short)h1; a[5] = (short)h2;
      a[6] = (short)l0; a[7] = (short)l1;
    } else {       // k8-15
      a[0] = (short)l2; a[1] = (short)ONE; a[2] = (short)ONE;
      a[3] = (short)l0; a[4] = (short)l1; a[5] = (short)l2;
      a[6] = 0; a[7] = 0;
    }
    afrag[rt] = a;
  }

  f32x16 r0, r1;
#pragma unroll
  for (int j = 0; j < 16; ++j) { r0[j] = -1e30f; r1[j] = -1e30f; }

  stage_chunk(yb, yf[0], 0, t);
  __syncthreads();

  for (int ch = 0; ch < NCHUNK; ++ch) {
    if (ch + 1 < NCHUNK)                       // overlap: fill other buffer
      stage_chunk(yb, yf[(ch + 1) & 1], ch + 1, t);
    const unsigned short* yfb = yf[ch & 1];
#pragma unroll
    for (int pr = 0; pr < CHUNK / 64; ++pr) {  // 8 col-tile pairs
      const unsigned short* pa = yfb + (size_t)(pr * 64 + lr) * CPITCH + g * 8;
      const bf16x8 bA = *(const bf16x8*)pa;                    // ds_read_b128
      const bf16x8 bB = *(const bf16x8*)(pa + 32 * CPITCH);
      const f32x16 d00 =
          __builtin_amdgcn_mfma_f32_32x32x16_bf16(afrag[0], bA, (f32x16){}, 0, 0, 0);
      const f32x16 d10 =
          __builtin_amdgcn_mfma_f32_32x32x16_bf16(afrag[1], bA, (f32x16){}, 0, 0, 0);
      const f32x16 d01 =
          __builtin_amdgcn_mfma_f32_32x32x16_bf16(afrag[0], bB, (f32x16){}, 0, 0, 0);
      const f32x16 d11 =
          __builtin_amdgcn_mfma_f32_32x32x16_bf16(afrag[1], bB, (f32x16){}, 0, 0, 0);
#pragma unroll
      for (int j = 0; j < 16; ++j) {           // 2 new values per v_max3
        r0[j] = fmaxf(fmaxf(r0[j], d00[j]), d01[j]);
        r1[j] = fmaxf(fmaxf(r1[j], d10[j]), d11[j]);
      }
    }
    __syncthreads();  // writes for ch+1 visible; reads of ch done before reuse
  }

  // ---- tail: full row-max via 32-lane butterfly, then weighted sum ----
  // C layout (m74/m101): col=lane&31, row=(j&3)+8*(j>>2)+4*(lane>>5).
  float acc = 0.0f;
#pragma unroll
  for (int rt = 0; rt < 2; ++rt) {
#pragma unroll
    for (int j = 0; j < 16; ++j) {
      float m = rt ? r1[j] : r0[j];
      m = fmaxf(m, __shfl_xor(m, 1, 64));
      m = fmaxf(m, __shfl_xor(m, 2, 64));
      m = fmaxf(m, __shfl_xor(m, 4, 64));
      m = fmaxf(m, __shfl_xor(m, 8, 64));
      m = fmaxf(m, __shfl_xor(m, 16, 64));     // allreduce within 32-half
      const int rl = (j & 3) + 8 * (j >> 2) + 4 * g;
      if (lr == rl) acc += fmaf(-2.0f, m, xn2[rt]);  // owner lane adds min-d2
    }
  }
  const int v_ = pair & (V_ - 1);
  acc *= ((v_ == 0) ? 2.0f : 1.0f) * (1.0f / (float)B_);
#pragma unroll
  for (int o = 32; o > 0; o >>= 1) acc += __shfl_down(acc, o, 64);
  if (lane == 0) red4[wv] = acc;
  __syncthreads();
  if (t == 0) bsum[bid] = (red4[0] + red4[1]) + (red4[2] + red4[3]);
}

__global__ __launch_bounds__(256) void chamfer_final(
    const float* __restrict__ bsum, float* __restrict__ out) {
  __shared__ float red4[4];
  const int t = threadIdx.x;
  float v = bsum[t] + bsum[t + 256];
#pragma unroll
  for (int o = 32; o > 0; o >>= 1) v += __shfl_down(v, o, 64);
  const int lane = t & 63, wid = t >> 6;
  if (lane == 0) red4[wid] = v;
  __syncthreads();
  if (t == 0) out[0] = (red4[0] + red4[1]) + (red4[2] + red4[3]);
}

extern "C" void kernel_launch(void* const* d_in, const int* in_sizes, int n_in,
                              void* d_out, int out_size, void* d_ws, size_t ws_size,
                              hipStream_t stream) {
  const float* X = (const float*)d_in[0];
  const float* T = (const float*)d_in[1];
  float* out = (float*)d_out;
  float* bsum = (float*)d_ws;  // 512 floats, fully overwritten each launch

  chamfer_main<<<GRID_, 256, 0, stream>>>(X, T, bsum);
  chamfer_final<<<1, 256, 0, stream>>>(bsum, out);
}